// Round 7
// baseline (222.276 us; speedup 1.0000x reference)
//
#include <hip/hip_runtime.h>
#include <math.h>

#define N_NODES 50000
#define N_EDGES 640000
#define HDIM    128
#define D_OUT   64
#define G_GRAPHS 500
#define EPSV    1e-5f
#define WPM     16384   // elements per packed 128x128 weight matrix

typedef __bf16 v8bf __attribute__((ext_vector_type(8)));
typedef float  f32x4 __attribute__((ext_vector_type(4)));

static __device__ __forceinline__ float bf_lo(unsigned u) {
    union { unsigned x; float f; } c; c.x = u << 16; return c.f;
}
static __device__ __forceinline__ float bf_hi(unsigned u) {
    union { unsigned x; float f; } c; c.x = u & 0xffff0000u; return c.f;
}

// ---------------------------------------------------------------------------
// Zero-init (replaces two latency-bound hipMemsetAsync fill dispatches)
// ---------------------------------------------------------------------------
__global__ void init_zero_kernel(int* __restrict__ cnt, float* __restrict__ pooled) {
    int i = blockIdx.x * blockDim.x + threadIdx.x;
    if (i < N_NODES) cnt[i] = 0;
    if (i < G_GRAPHS * 128) pooled[i] = 0.f;
}

// ---------------------------------------------------------------------------
// Degrees
// ---------------------------------------------------------------------------
__global__ void count_deg_kernel(const int* __restrict__ dst, int* __restrict__ cnt, int E) {
    int i = blockIdx.x * blockDim.x + threadIdx.x;
    if (i < E) atomicAdd(&cnt[dst[i]], 1);
}

// ---------------------------------------------------------------------------
// 3-phase parallel exclusive scan (cnt -> ofs, cursor) + degree finalize
// ---------------------------------------------------------------------------
__global__ __launch_bounds__(1024) void scan_block_kernel(
    const int* __restrict__ cnt, int* __restrict__ ofs,
    int* __restrict__ btot, int n)
{
    __shared__ int wsum[16];
    const int tid  = threadIdx.x;
    const int lane = tid & 63;
    const int wid  = tid >> 6;
    int i = blockIdx.x * 1024 + tid;
    int v = (i < n) ? cnt[i] : 0;
    int x = v;
    #pragma unroll
    for (int o = 1; o < 64; o <<= 1) {
        int t = __shfl_up(x, o);
        if (lane >= o) x += t;
    }
    if (lane == 63) wsum[wid] = x;
    __syncthreads();
    if (wid == 0) {
        int y = (lane < 16) ? wsum[lane] : 0;
        #pragma unroll
        for (int o = 1; o < 16; o <<= 1) {
            int t = __shfl_up(y, o);
            if (lane >= o) y += t;
        }
        if (lane < 16) wsum[lane] = y;
    }
    __syncthreads();
    int wbase = (wid == 0) ? 0 : wsum[wid - 1];
    if (i < n) ofs[i] = wbase + x - v;
    if (tid == 1023) btot[blockIdx.x] = wbase + x;
}

__global__ __launch_bounds__(64) void scan_tot_kernel(
    const int* __restrict__ btot, int* __restrict__ bbase,
    int* __restrict__ ofs, int nb, int n)
{
    int i = threadIdx.x;
    int v = (i < nb) ? btot[i] : 0;
    int x = v;
    #pragma unroll
    for (int o = 1; o < 64; o <<= 1) {
        int t = __shfl_up(x, o);
        if (i >= o) x += t;
    }
    if (i < nb) bbase[i] = x - v;
    if (i == nb - 1) ofs[n] = x;
}

// scan finalize + degree terms (fused elementwise pass)
__global__ void scan_add_kernel(int* __restrict__ ofs, int* __restrict__ cursor,
                                const int* __restrict__ bbase,
                                const int* __restrict__ cnt,
                                float* __restrict__ dinv,
                                float* __restrict__ rdegn, int n) {
    int i = blockIdx.x * blockDim.x + threadIdx.x;
    if (i < n) {
        int o = ofs[i] + bbase[i >> 10];
        ofs[i] = o;
        cursor[i] = o;
        float c = (float)cnt[i];
        dinv[i]  = rsqrtf(c + 1.0f);
        rdegn[i] = 1.0f / fmaxf(c, 1.0f);
    }
}

// CSR fill with packed {src, dinv[src]} entries
__global__ void csr_fill_kernel(const int* __restrict__ src, const int* __restrict__ dst,
                                int* __restrict__ cursor, const float* __restrict__ dinv,
                                int2* __restrict__ csr, int E) {
    int e = blockIdx.x * blockDim.x + threadIdx.x;
    if (e < E) {
        int s = src[e];
        int d = dst[e];
        int pos = atomicAdd(&cursor[d], 1);
        csr[pos] = make_int2(s, __float_as_int(dinv[s]));
    }
}

// ---------------------------------------------------------------------------
// Pack 7 f32 128x128 weights into bf16 MFMA B-fragment order, with the
// conv-softmax weights FOLDED IN:
//   m=0: pre_w    m=1,2: wc0[l]*gcn_w[l]   m=3,4: wc1[l]*sage_ws[l]
//   m=5,6: wc1[l]*sage_wn[l]
// ---------------------------------------------------------------------------
__global__ void pack_weights_kernel(const float* __restrict__ pre_w,
                                    const float* __restrict__ gcn_w,
                                    const float* __restrict__ sws,
                                    const float* __restrict__ swn,
                                    const float* __restrict__ a_conv,
                                    __bf16* __restrict__ Wp)
{
    int t = blockIdx.x * blockDim.x + threadIdx.x;
    if (t >= 7 * 2048) return;
    int m    = t >> 11;
    int r    = t & 2047;
    int lane = r & 63;
    int fb   = r >> 6;           // kc*8 + cb
    int kc   = fb >> 3;
    int cb   = fb & 7;
    const float* W = pre_w;
    float scale = 1.f;
    if (m > 0) {
        int type = (m - 1) >> 1;     // 0=gcn, 1=sage_ws, 2=sage_wn
        int l    = (m - 1) & 1;
        float c0 = a_conv[l * 2], c1 = a_conv[l * 2 + 1];
        float mx = fmaxf(c0, c1);
        float e0 = __expf(c0 - mx), e1 = __expf(c1 - mx);
        float wc0 = e0 / (e0 + e1);
        scale = (type == 0) ? wc0 : (1.f - wc0);
        W = (type == 0) ? gcn_w + (size_t)l * WPM
          : (type == 1) ? sws   + (size_t)l * WPM
                        : swn   + (size_t)l * WPM;
    }
    int k0  = kc * 32 + (lane >> 4) * 8;
    int col = cb * 16 + (lane & 15);
    __bf16* out = Wp + (size_t)m * WPM + ((size_t)fb * 64 + lane) * 8;
    #pragma unroll
    for (int i = 0; i < 8; i++)
        out[i] = (__bf16)(scale * W[(size_t)(k0 + i) * 128 + col]);
}

// ---------------------------------------------------------------------------
// Pull-gather (bf16): one wave per dst node (50k waves for TLP), packed csr,
// 2x-unrolled 4-edges-per-iter (16 lanes x 16B per 256B row).
// ---------------------------------------------------------------------------
__global__ __launch_bounds__(256) void fused_gather_bf16(
    const __bf16* __restrict__ hb,
    const int2* __restrict__ csr,
    const int* __restrict__ ofs,
    const float* __restrict__ dinv,
    const float* __restrict__ rdegn,
    __bf16* __restrict__ aggGb,
    __bf16* __restrict__ meanb, int n)
{
    int w = threadIdx.x >> 6;
    int lane = threadIdx.x & 63;
    int d = blockIdx.x * 4 + w;
    if (d >= n) return;
    int beg = ofs[d], end = ofs[d + 1];
    float did = dinv[d];
    int q  = lane >> 4;
    int c8 = (lane & 15) * 8;

    float aG[8] = {0, 0, 0, 0, 0, 0, 0, 0};
    float aS[8] = {0, 0, 0, 0, 0, 0, 0, 0};

    for (int p = beg; p < end; p += 8) {
        int pp0 = p + q;
        int pp1 = p + 4 + q;
        bool ok0 = pp0 < end;
        bool ok1 = pp1 < end;
        int2 e0 = csr[ok0 ? pp0 : beg];
        int2 e1 = csr[ok1 ? pp1 : beg];
        uint4 u0 = *(const uint4*)(hb + (size_t)e0.x * 128 + c8);
        uint4 u1 = *(const uint4*)(hb + (size_t)e1.x * 128 + c8);
        float w0 = ok0 ? __int_as_float(e0.y) * did : 0.f;
        float w1 = ok1 ? __int_as_float(e1.y) * did : 0.f;
        float m0 = ok0 ? 1.f : 0.f;
        float m1 = ok1 ? 1.f : 0.f;
        float v0[8] = { bf_lo(u0.x), bf_hi(u0.x), bf_lo(u0.y), bf_hi(u0.y),
                        bf_lo(u0.z), bf_hi(u0.z), bf_lo(u0.w), bf_hi(u0.w) };
        float v1[8] = { bf_lo(u1.x), bf_hi(u1.x), bf_lo(u1.y), bf_hi(u1.y),
                        bf_lo(u1.z), bf_hi(u1.z), bf_lo(u1.w), bf_hi(u1.w) };
        #pragma unroll
        for (int j = 0; j < 8; j++) {
            aG[j] = fmaf(v0[j], w0, aG[j]);
            aS[j] = fmaf(v0[j], m0, aS[j]);
            aG[j] = fmaf(v1[j], w1, aG[j]);
            aS[j] = fmaf(v1[j], m1, aS[j]);
        }
    }
    #pragma unroll
    for (int j = 0; j < 8; j++) {
        aG[j] += __shfl_xor(aG[j], 16);
        aG[j] += __shfl_xor(aG[j], 32);
        aS[j] += __shfl_xor(aS[j], 16);
        aS[j] += __shfl_xor(aS[j], 32);
    }
    if (q == 0) {
        uint4 ud = *(const uint4*)(hb + (size_t)d * 128 + c8);
        float vd[8] = { bf_lo(ud.x), bf_hi(ud.x), bf_lo(ud.y), bf_hi(ud.y),
                        bf_lo(ud.z), bf_hi(ud.z), bf_lo(ud.w), bf_hi(ud.w) };
        float sl = did * did;
        float rd = rdegn[d];
        union { __bf16 b[8]; uint4 u; } pg, pm;
        #pragma unroll
        for (int j = 0; j < 8; j++) {
            pg.b[j] = (__bf16)fmaf(vd[j], sl, aG[j]);
            pm.b[j] = (__bf16)(aS[j] * rd);
        }
        *(uint4*)(aggGb + (size_t)d * 128 + c8) = pg.u;
        *(uint4*)(meanb + (size_t)d * 128 + c8) = pm.u;
    }
}

// ---------------------------------------------------------------------------
// Pre-MLP: h_bf16 = x_f32 @ pre_w + pre_b, via MFMA; pre_w staged in LDS
// (32 KB once per block). No early returns (barrier); ragged tail clamped.
// ---------------------------------------------------------------------------
__global__ __launch_bounds__(256) void pre_gemm_mfma(
    const float* __restrict__ x, const __bf16* __restrict__ Wp0,
    const float* __restrict__ pre_b, __bf16* __restrict__ hb, int n)
{
    __shared__ __bf16 wlds[WPM];               // 32 KB
    const int tid  = threadIdx.x;
    const int w    = tid >> 6;
    const int lane = tid & 63;
    const int r0 = blockIdx.x * 64 + w * 16;
    int rl = r0 + (lane & 15);
    if (rl >= n) rl = n - 1;
    const int kg = lane >> 4;

    // stage packed pre_w: 2048 uint4 across 256 threads
    {
        uint4* lds4 = (uint4*)wlds;
        const uint4* g = (const uint4*)Wp0;
        #pragma unroll
        for (int it = 0; it < 8; it++)
            lds4[it * 256 + tid] = g[it * 256 + tid];
    }

    f32x4 acc[8];
    #pragma unroll
    for (int cb = 0; cb < 8; cb++) acc[cb] = (f32x4)(0.f);

    // A fragments (f32 -> bf16 in-register), hoisted before barrier
    v8bf af[4];
    #pragma unroll
    for (int kc = 0; kc < 4; kc++) {
        const float* ap = x + (size_t)rl * 128 + kc * 32 + kg * 8;
        float4 a0 = *(const float4*)ap;
        float4 a1 = *(const float4*)(ap + 4);
        v8bf v;
        v[0] = (__bf16)a0.x; v[1] = (__bf16)a0.y;
        v[2] = (__bf16)a0.z; v[3] = (__bf16)a0.w;
        v[4] = (__bf16)a1.x; v[5] = (__bf16)a1.y;
        v[6] = (__bf16)a1.z; v[7] = (__bf16)a1.w;
        af[kc] = v;
    }
    __syncthreads();

    #pragma unroll
    for (int kc = 0; kc < 4; kc++) {
        #pragma unroll
        for (int cb = 0; cb < 8; cb++) {
            int bo = ((kc * 8 + cb) * 64 + lane) * 8;
            acc[cb] = __builtin_amdgcn_mfma_f32_16x16x32_bf16(
                af[kc], *(const v8bf*)&wlds[bo], acc[cb], 0, 0, 0);
        }
    }
    int cl = lane & 15;
    #pragma unroll
    for (int cb = 0; cb < 8; cb++) {
        float bias = pre_b[cb * 16 + cl];
        #pragma unroll
        for (int j = 0; j < 4; j++) {
            int r = r0 + kg * 4 + j;
            if (r < n) hb[(size_t)r * 128 + cb * 16 + cl] = (__bf16)(acc[cb][j] + bias);
        }
    }
}

// ---------------------------------------------------------------------------
// LAYER GEMM: single K=384 MFMA stream (conv softmax folded into weights),
// B-fragments staged in LDS (two 48KB phases per block, cooperatively).
// Then LN blend + act blend, write h_out (bf16).
// ---------------------------------------------------------------------------
__global__ __launch_bounds__(256, 3) void layer_gemm_kernel(
    const __bf16* __restrict__ aggGb, const __bf16* __restrict__ hin,
    const __bf16* __restrict__ meanb,
    const __bf16* __restrict__ WpG, const __bf16* __restrict__ WpS,
    const __bf16* __restrict__ WpN,
    const float* __restrict__ gcn_b,
    const float* __restrict__ lng, const float* __restrict__ lnb,
    const float* __restrict__ anorm, const float* __restrict__ aact,
    const float* __restrict__ aconv,
    __bf16* __restrict__ hout, int n)
{
    __shared__ __bf16 wlds[3 * 16 * 64 * 8];   // 48 KB: one K-half of G,S,N
    const int tid  = threadIdx.x;
    const int w    = tid >> 6;
    const int lane = tid & 63;
    const int r0 = blockIdx.x * 64 + w * 16;
    int rl = r0 + (lane & 15);
    if (rl >= n) rl = n - 1;
    const int kg = lane >> 4;

    // A fragments (all 12 up front; overlaps with staging)
    v8bf af[12];
    #pragma unroll
    for (int kc = 0; kc < 4; kc++) {
        size_t ao = (size_t)rl * 128 + kc * 32 + kg * 8;
        af[kc]     = *(const v8bf*)(aggGb + ao);
        af[4 + kc] = *(const v8bf*)(hin   + ao);
        af[8 + kc] = *(const v8bf*)(meanb + ao);
    }

    f32x4 acc[8];
    #pragma unroll
    for (int cb = 0; cb < 8; cb++) acc[cb] = (f32x4)(0.f);

    uint4* lds4 = (uint4*)wlds;

    // ---- phase A: stage K-half 0 (fb 0..15 of each matrix) ----
    {
        const uint4* gG = (const uint4*)WpG;
        const uint4* gS = (const uint4*)WpS;
        const uint4* gN = (const uint4*)WpN;
        #pragma unroll
        for (int it = 0; it < 12; it++) {
            int idx = it * 256 + tid;          // 0..3071
            int m = idx >> 10;
            int r = idx & 1023;
            const uint4* g = (m == 0) ? gG : (m == 1) ? gS : gN;
            lds4[idx] = g[r];
        }
    }
    __syncthreads();
    #pragma unroll
    for (int kc2 = 0; kc2 < 2; kc2++) {
        #pragma unroll
        for (int cb = 0; cb < 8; cb++) {
            int bo = ((kc2 * 8 + cb) * 64 + lane) * 8;
            acc[cb] = __builtin_amdgcn_mfma_f32_16x16x32_bf16(
                af[kc2], *(const v8bf*)&wlds[bo], acc[cb], 0, 0, 0);
            acc[cb] = __builtin_amdgcn_mfma_f32_16x16x32_bf16(
                af[4 + kc2], *(const v8bf*)&wlds[8192 + bo], acc[cb], 0, 0, 0);
            acc[cb] = __builtin_amdgcn_mfma_f32_16x16x32_bf16(
                af[8 + kc2], *(const v8bf*)&wlds[16384 + bo], acc[cb], 0, 0, 0);
        }
    }
    __syncthreads();

    // ---- phase B: stage K-half 1 (fb 16..31) ----
    {
        const uint4* gG = (const uint4*)WpG + 1024;
        const uint4* gS = (const uint4*)WpS + 1024;
        const uint4* gN = (const uint4*)WpN + 1024;
        #pragma unroll
        for (int it = 0; it < 12; it++) {
            int idx = it * 256 + tid;
            int m = idx >> 10;
            int r = idx & 1023;
            const uint4* g = (m == 0) ? gG : (m == 1) ? gS : gN;
            lds4[idx] = g[r];
        }
    }
    __syncthreads();
    #pragma unroll
    for (int kc2 = 0; kc2 < 2; kc2++) {
        #pragma unroll
        for (int cb = 0; cb < 8; cb++) {
            int bo = ((kc2 * 8 + cb) * 64 + lane) * 8;
            acc[cb] = __builtin_amdgcn_mfma_f32_16x16x32_bf16(
                af[2 + kc2], *(const v8bf*)&wlds[bo], acc[cb], 0, 0, 0);
            acc[cb] = __builtin_amdgcn_mfma_f32_16x16x32_bf16(
                af[6 + kc2], *(const v8bf*)&wlds[8192 + bo], acc[cb], 0, 0, 0);
            acc[cb] = __builtin_amdgcn_mfma_f32_16x16x32_bf16(
                af[10 + kc2], *(const v8bf*)&wlds[16384 + bo], acc[cb], 0, 0, 0);
        }
    }

    // ---- epilogue: bias, LN blend, activation blend ----
    float c0 = aconv[0], c1 = aconv[1];
    float m = fmaxf(c0, c1);
    float e0 = __expf(c0 - m), e1 = __expf(c1 - m);
    float wc0 = e0 / (e0 + e1);
    float q0 = anorm[0], q1 = anorm[1];
    m = fmaxf(q0, q1);
    e0 = __expf(q0 - m); e1 = __expf(q1 - m);
    float wn0 = e0 / (e0 + e1), wn1 = 1.f - wn0;
    float a0 = aact[0], a1 = aact[1], a2 = aact[2];
    m = fmaxf(fmaxf(a0, a1), a2);
    float f0 = __expf(a0 - m), f1 = __expf(a1 - m), f2 = __expf(a2 - m);
    float fs = 1.f / (f0 + f1 + f2);
    float wa0 = f0 * fs, wa1 = f1 * fs, wa2 = f2 * fs;

    int cl = lane & 15;
    float gbF[8], lg[8], lb[8];
    #pragma unroll
    for (int cb = 0; cb < 8; cb++) {
        int c = cb * 16 + cl;
        gbF[cb] = wc0 * gcn_b[c]; lg[cb] = lng[c]; lb[cb] = lnb[c];
    }

    float s[4] = {0, 0, 0, 0}, s2[4] = {0, 0, 0, 0};
    #pragma unroll
    for (int cb = 0; cb < 8; cb++)
        #pragma unroll
        for (int j = 0; j < 4; j++) {
            float tv = acc[cb][j] + gbF[cb];
            acc[cb][j] = tv;
            s[j] += tv;
            s2[j] = fmaf(tv, tv, s2[j]);
        }
    #pragma unroll
    for (int o = 1; o < 16; o <<= 1)
        #pragma unroll
        for (int j = 0; j < 4; j++) {
            s[j]  += __shfl_xor(s[j], o);
            s2[j] += __shfl_xor(s2[j], o);
        }
    float mu[4], rs[4];
    #pragma unroll
    for (int j = 0; j < 4; j++) {
        mu[j] = s[j] * (1.f / 128.f);
        float var = s2[j] * (1.f / 128.f) - mu[j] * mu[j];
        rs[j] = rsqrtf(var + EPSV);
    }

    #pragma unroll
    for (int j = 0; j < 4; j++) {
        int r = r0 + kg * 4 + j;
        if (r >= n) continue;
        #pragma unroll
        for (int cb = 0; cb < 8; cb++) {
            float tv = acc[cb][j];
            float ln = (tv - mu[j]) * rs[j] * lg[cb] + lb[cb];
            float hv = wn0 * ln + wn1 * tv;
            float rl_ = fmaxf(hv, 0.f);
            float ex2 = __expf(2.f * hv);
            float th = 1.f - 2.f * __builtin_amdgcn_rcpf(ex2 + 1.f);
            float el = hv > 0.f ? hv : __expf(hv) - 1.f;
            float out = wa0 * rl_ + wa1 * th + wa2 * el;
            hout[(size_t)r * 128 + cb * 16 + cl] = (__bf16)out;
        }
    }
}

// ---------------------------------------------------------------------------
// Pooling: sum h1+h2 (bf16), batch sorted -> run-length accumulate.
// ---------------------------------------------------------------------------
__global__ __launch_bounds__(256) void pool_sum_kernel(
    const __bf16* __restrict__ h1, const __bf16* __restrict__ h2,
    const int* __restrict__ batch, float* __restrict__ pooled, int n)
{
    int c2  = (threadIdx.x & 63) * 2;
    int seg = threadIdx.x >> 6;
    int n0  = blockIdx.x * 128 + seg * 32;
    int g_cur = -1;
    float acc0 = 0.f, acc1 = 0.f;
    for (int i = 0; i < 32; i++) {
        int node = n0 + i;
        if (node >= n) break;
        int g = batch[node];
        if (g != g_cur) {
            if (g_cur >= 0) {
                atomicAdd(&pooled[(size_t)g_cur * 128 + c2], acc0);
                atomicAdd(&pooled[(size_t)g_cur * 128 + c2 + 1], acc1);
            }
            g_cur = g; acc0 = 0.f; acc1 = 0.f;
        }
        unsigned u1 = *(const unsigned*)(h1 + (size_t)node * 128 + c2);
        unsigned u2 = *(const unsigned*)(h2 + (size_t)node * 128 + c2);
        acc0 += bf_lo(u1) + bf_lo(u2);
        acc1 += bf_hi(u1) + bf_hi(u2);
    }
    if (g_cur >= 0) {
        atomicAdd(&pooled[(size_t)g_cur * 128 + c2], acc0);
        atomicAdd(&pooled[(size_t)g_cur * 128 + c2 + 1], acc1);
    }
}

__global__ __launch_bounds__(64) void post_gemm_kernel(
    const float* __restrict__ pooled, const float* __restrict__ W,
    const float* __restrict__ b, float* __restrict__ out)
{
    __shared__ float p_s[128];
    int g = blockIdx.x;
    int j = threadIdx.x;
    p_s[j]      = pooled[(size_t)g * 128 + j];
    p_s[j + 64] = pooled[(size_t)g * 128 + 64 + j];
    __syncthreads();
    float acc = b[j];
    #pragma unroll
    for (int k = 0; k < 128; k++)
        acc = fmaf(p_s[k], W[k * 64 + j], acc);
    out[(size_t)g * 64 + j] = acc;
}

// ---------------------------------------------------------------------------
extern "C" void kernel_launch(void* const* d_in, const int* in_sizes, int n_in,
                              void* d_out, int out_size, void* d_ws, size_t ws_size,
                              hipStream_t stream)
{
    const float* x       = (const float*)d_in[0];
    const int*   ei      = (const int*)d_in[1];
    const int*   batch   = (const int*)d_in[2];
    const float* pre_w   = (const float*)d_in[3];
    const float* pre_b   = (const float*)d_in[4];
    const float* post_w  = (const float*)d_in[5];
    const float* post_b  = (const float*)d_in[6];
    const float* gcn_w   = (const float*)d_in[7];
    const float* gcn_b   = (const float*)d_in[8];
    const float* sage_ws = (const float*)d_in[9];
    const float* sage_wn = (const float*)d_in[10];
    const float* ln_g    = (const float*)d_in[11];
    const float* ln_b    = (const float*)d_in[12];
    const float* a_conv  = (const float*)d_in[13];
    const float* a_norm  = (const float*)d_in[14];
    const float* a_act   = (const float*)d_in[15];

    const int* src = ei;
    const int* dst = ei + N_EDGES;

    char* wsp = (char*)d_ws;
    size_t off = 0;
    auto alloc = [&](size_t bytes) {
        char* p = wsp + off;
        off += (bytes + 255) & ~(size_t)255;
        return p;
    };
    const size_t NHB = (size_t)N_NODES * 128 * sizeof(__bf16);   // 12.8 MB
    __bf16* hb0    = (__bf16*)alloc(NHB);
    __bf16* h1b    = (__bf16*)alloc(NHB);
    __bf16* h2b    = (__bf16*)alloc(NHB);
    __bf16* aggGb  = (__bf16*)alloc(NHB);
    __bf16* meanb  = (__bf16*)alloc(NHB);
    __bf16* Wp     = (__bf16*)alloc((size_t)7 * WPM * sizeof(__bf16));
    float*  dinv   = (float*)alloc(N_NODES * sizeof(float));
    float*  rdegn  = (float*)alloc(N_NODES * sizeof(float));
    int*    cnt    = (int*)alloc(N_NODES * sizeof(int));
    int*    ofs    = (int*)alloc((N_NODES + 1) * sizeof(int));
    int*    cursor = (int*)alloc(N_NODES * sizeof(int));
    int2*   csr    = (int2*)alloc((size_t)N_EDGES * sizeof(int2));
    float*  pooled = (float*)alloc((size_t)G_GRAPHS * 128 * sizeof(float));
    int*    btot   = (int*)alloc(64 * sizeof(int));
    int*    bbase  = (int*)alloc(64 * sizeof(int));

    const int NB_SCAN = (N_NODES + 1023) / 1024;
    const int GEMM_BLOCKS = (N_NODES + 63) / 64;
    const int GATHER_BLOCKS = (N_NODES + 3) / 4;

    init_zero_kernel<<<(G_GRAPHS * 128 + 255) / 256, 256, 0, stream>>>(cnt, pooled);

    pack_weights_kernel<<<(7 * 2048 + 255) / 256, 256, 0, stream>>>(
        pre_w, gcn_w, sage_ws, sage_wn, a_conv, Wp);

    count_deg_kernel<<<(N_EDGES + 255) / 256, 256, 0, stream>>>(dst, cnt, N_EDGES);
    scan_block_kernel<<<NB_SCAN, 1024, 0, stream>>>(cnt, ofs, btot, N_NODES);
    scan_tot_kernel<<<1, 64, 0, stream>>>(btot, bbase, ofs, NB_SCAN, N_NODES);
    scan_add_kernel<<<(N_NODES + 255) / 256, 256, 0, stream>>>(
        ofs, cursor, bbase, cnt, dinv, rdegn, N_NODES);
    csr_fill_kernel<<<(N_EDGES + 255) / 256, 256, 0, stream>>>(
        src, dst, cursor, dinv, csr, N_EDGES);

    pre_gemm_mfma<<<GEMM_BLOCKS, 256, 0, stream>>>(x, Wp, pre_b, hb0, N_NODES);

    const __bf16* hin[2]  = { hb0, h1b };
    __bf16*       hout[2] = { h1b, h2b };
    for (int l = 0; l < 2; l++) {
        fused_gather_bf16<<<GATHER_BLOCKS, 256, 0, stream>>>(
            hin[l], csr, ofs, dinv, rdegn, aggGb, meanb, N_NODES);
        layer_gemm_kernel<<<GEMM_BLOCKS, 256, 0, stream>>>(
            aggGb, hin[l], meanb,
            Wp + (size_t)(1 + l) * WPM, Wp + (size_t)(3 + l) * WPM, Wp + (size_t)(5 + l) * WPM,
            gcn_b + l * 128, ln_g + l * 128, ln_b + l * 128,
            a_norm + l * 2, a_act + l * 3, a_conv + l * 2,
            hout[l], N_NODES);
    }

    pool_sum_kernel<<<(N_NODES + 127) / 128, 256, 0, stream>>>(h1b, h2b, batch, pooled, N_NODES);
    post_gemm_kernel<<<G_GRAPHS, 64, 0, stream>>>(pooled, post_w, post_b, (float*)d_out);
}

// Round 8
// 218.831 us; speedup vs baseline: 1.0157x; 1.0157x over previous
//
#include <hip/hip_runtime.h>
#include <math.h>

#define N_NODES 50000
#define N_EDGES 640000
#define HDIM    128
#define D_OUT   64
#define G_GRAPHS 500
#define EPSV    1e-5f
#define WPM     16384   // elements per packed 128x128 weight matrix

typedef __bf16 v8bf __attribute__((ext_vector_type(8)));
typedef float  f32x4 __attribute__((ext_vector_type(4)));

static __device__ __forceinline__ float bf_lo(unsigned u) {
    union { unsigned x; float f; } c; c.x = u << 16; return c.f;
}
static __device__ __forceinline__ float bf_hi(unsigned u) {
    union { unsigned x; float f; } c; c.x = u & 0xffff0000u; return c.f;
}

// ---------------------------------------------------------------------------
// Setup: zero cnt+pooled AND pack 7 f32 128x128 weights into bf16 MFMA
// B-fragment order with conv-softmax folded in:
//   m=0: pre_w   m=1,2: wc0[l]*gcn_w[l]  m=3,4: wc1[l]*sage_ws[l]
//   m=5,6: wc1[l]*sage_wn[l]
// ---------------------------------------------------------------------------
__global__ void setup_kernel(const float* __restrict__ pre_w,
                             const float* __restrict__ gcn_w,
                             const float* __restrict__ sws,
                             const float* __restrict__ swn,
                             const float* __restrict__ a_conv,
                             __bf16* __restrict__ Wp,
                             int* __restrict__ cnt,
                             float* __restrict__ pooled)
{
    int t = blockIdx.x * blockDim.x + threadIdx.x;
    if (t < N_NODES) cnt[t] = 0;
    if (t < G_GRAPHS * 128) pooled[t] = 0.f;
    if (t >= 7 * 2048) return;
    int m    = t >> 11;
    int r    = t & 2047;
    int lane = r & 63;
    int fb   = r >> 6;           // kc*8 + cb
    int kc   = fb >> 3;
    int cb   = fb & 7;
    const float* W = pre_w;
    float scale = 1.f;
    if (m > 0) {
        int type = (m - 1) >> 1;     // 0=gcn, 1=sage_ws, 2=sage_wn
        int l    = (m - 1) & 1;
        float c0 = a_conv[l * 2], c1 = a_conv[l * 2 + 1];
        float mx = fmaxf(c0, c1);
        float e0 = __expf(c0 - mx), e1 = __expf(c1 - mx);
        float wc0 = e0 / (e0 + e1);
        scale = (type == 0) ? wc0 : (1.f - wc0);
        W = (type == 0) ? gcn_w + (size_t)l * WPM
          : (type == 1) ? sws   + (size_t)l * WPM
                        : swn   + (size_t)l * WPM;
    }
    int k0  = kc * 32 + (lane >> 4) * 8;
    int col = cb * 16 + (lane & 15);
    __bf16* out = Wp + (size_t)m * WPM + ((size_t)fb * 64 + lane) * 8;
    #pragma unroll
    for (int i = 0; i < 8; i++)
        out[i] = (__bf16)(scale * W[(size_t)(k0 + i) * 128 + col]);
}

// ---------------------------------------------------------------------------
// Degrees
// ---------------------------------------------------------------------------
__global__ void count_deg_kernel(const int* __restrict__ dst, int* __restrict__ cnt, int E) {
    int i = blockIdx.x * blockDim.x + threadIdx.x;
    if (i < E) atomicAdd(&cnt[dst[i]], 1);
}

// ---------------------------------------------------------------------------
// 3-phase parallel exclusive scan; final phase emits packed per-node header
// hdr[i] = {beg, end, dinv_bits, rdegn_bits} and cursor/dinv for csr_fill.
// ---------------------------------------------------------------------------
__global__ __launch_bounds__(1024) void scan_block_kernel(
    const int* __restrict__ cnt, int* __restrict__ ofs,
    int* __restrict__ btot, int n)
{
    __shared__ int wsum[16];
    const int tid  = threadIdx.x;
    const int lane = tid & 63;
    const int wid  = tid >> 6;
    int i = blockIdx.x * 1024 + tid;
    int v = (i < n) ? cnt[i] : 0;
    int x = v;
    #pragma unroll
    for (int o = 1; o < 64; o <<= 1) {
        int t = __shfl_up(x, o);
        if (lane >= o) x += t;
    }
    if (lane == 63) wsum[wid] = x;
    __syncthreads();
    if (wid == 0) {
        int y = (lane < 16) ? wsum[lane] : 0;
        #pragma unroll
        for (int o = 1; o < 16; o <<= 1) {
            int t = __shfl_up(y, o);
            if (lane >= o) y += t;
        }
        if (lane < 16) wsum[lane] = y;
    }
    __syncthreads();
    int wbase = (wid == 0) ? 0 : wsum[wid - 1];
    if (i < n) ofs[i] = wbase + x - v;      // chunk-local exclusive
    if (tid == 1023) btot[blockIdx.x] = wbase + x;
}

__global__ __launch_bounds__(64) void scan_tot_kernel(
    const int* __restrict__ btot, int* __restrict__ bbase, int nb)
{
    int i = threadIdx.x;
    int v = (i < nb) ? btot[i] : 0;
    int x = v;
    #pragma unroll
    for (int o = 1; o < 64; o <<= 1) {
        int t = __shfl_up(x, o);
        if (i >= o) x += t;
    }
    if (i < nb) bbase[i] = x - v;
}

__global__ void scan_add_kernel(const int* __restrict__ ofs,
                                int* __restrict__ cursor,
                                const int* __restrict__ bbase,
                                const int* __restrict__ cnt,
                                float* __restrict__ dinv,
                                int4* __restrict__ hdr, int n) {
    int i = blockIdx.x * blockDim.x + threadIdx.x;
    if (i < n) {
        int o = ofs[i] + bbase[i >> 10];
        cursor[i] = o;
        int c = cnt[i];
        float cf = (float)c;
        float di = rsqrtf(cf + 1.0f);
        float rd = 1.0f / fmaxf(cf, 1.0f);
        dinv[i] = di;
        hdr[i] = make_int4(o, o + c, __float_as_int(di), __float_as_int(rd));
    }
}

// CSR fill with packed {src, dinv[src]} entries
__global__ void csr_fill_kernel(const int* __restrict__ src, const int* __restrict__ dst,
                                int* __restrict__ cursor, const float* __restrict__ dinv,
                                int2* __restrict__ csr, int E) {
    int e = blockIdx.x * blockDim.x + threadIdx.x;
    if (e < E) {
        int s = src[e];
        int d = dst[e];
        int pos = atomicAdd(&cursor[d], 1);
        csr[pos] = make_int2(s, __float_as_int(dinv[s]));
    }
}

// ---------------------------------------------------------------------------
// Pull-gather (bf16): one wave per dst node, packed header (one int4 load),
// 16 edges per iteration (4 independent csr loads + 4 row loads in flight
// per 16-lane group). f32 accumulation, cross-quarter shfl reduce.
// ---------------------------------------------------------------------------
__global__ __launch_bounds__(256) void fused_gather_bf16(
    const __bf16* __restrict__ hb,
    const int2* __restrict__ csr,
    const int4* __restrict__ hdr,
    __bf16* __restrict__ aggGb,
    __bf16* __restrict__ meanb, int n)
{
    int w = threadIdx.x >> 6;
    int lane = threadIdx.x & 63;
    int d = blockIdx.x * 4 + w;
    if (d >= n) return;
    int4 h4 = hdr[d];
    int beg = h4.x, end = h4.y;
    float did = __int_as_float(h4.z);
    float rd  = __int_as_float(h4.w);
    int q  = lane >> 4;
    int c8 = (lane & 15) * 8;

    float aG[8] = {0, 0, 0, 0, 0, 0, 0, 0};
    float aS[8] = {0, 0, 0, 0, 0, 0, 0, 0};

    for (int p = beg; p < end; p += 16) {
        bool ok[4];
        int2 e[4];
        #pragma unroll
        for (int k = 0; k < 4; k++) {
            int idx = p + 4 * k + q;
            ok[k] = idx < end;
            e[k] = csr[ok[k] ? idx : beg];
        }
        uint4 u[4];
        #pragma unroll
        for (int k = 0; k < 4; k++)
            u[k] = *(const uint4*)(hb + (size_t)e[k].x * 128 + c8);
        #pragma unroll
        for (int k = 0; k < 4; k++) {
            float wk = ok[k] ? __int_as_float(e[k].y) * did : 0.f;
            float mk = ok[k] ? 1.f : 0.f;
            float v[8] = { bf_lo(u[k].x), bf_hi(u[k].x), bf_lo(u[k].y), bf_hi(u[k].y),
                           bf_lo(u[k].z), bf_hi(u[k].z), bf_lo(u[k].w), bf_hi(u[k].w) };
            #pragma unroll
            for (int j = 0; j < 8; j++) {
                aG[j] = fmaf(v[j], wk, aG[j]);
                aS[j] = fmaf(v[j], mk, aS[j]);
            }
        }
    }
    #pragma unroll
    for (int j = 0; j < 8; j++) {
        aG[j] += __shfl_xor(aG[j], 16);
        aG[j] += __shfl_xor(aG[j], 32);
        aS[j] += __shfl_xor(aS[j], 16);
        aS[j] += __shfl_xor(aS[j], 32);
    }
    if (q == 0) {
        uint4 ud = *(const uint4*)(hb + (size_t)d * 128 + c8);
        float vd[8] = { bf_lo(ud.x), bf_hi(ud.x), bf_lo(ud.y), bf_hi(ud.y),
                        bf_lo(ud.z), bf_hi(ud.z), bf_lo(ud.w), bf_hi(ud.w) };
        float sl = did * did;
        union { __bf16 b[8]; uint4 u; } pg, pm;
        #pragma unroll
        for (int j = 0; j < 8; j++) {
            pg.b[j] = (__bf16)fmaf(vd[j], sl, aG[j]);
            pm.b[j] = (__bf16)(aS[j] * rd);
        }
        *(uint4*)(aggGb + (size_t)d * 128 + c8) = pg.u;
        *(uint4*)(meanb + (size_t)d * 128 + c8) = pm.u;
    }
}

// ---------------------------------------------------------------------------
// Pre-MLP: h_bf16 = x_f32 @ pre_w + pre_b, via MFMA; pre_w staged in LDS.
// ---------------------------------------------------------------------------
__global__ __launch_bounds__(256) void pre_gemm_mfma(
    const float* __restrict__ x, const __bf16* __restrict__ Wp0,
    const float* __restrict__ pre_b, __bf16* __restrict__ hb, int n)
{
    __shared__ __bf16 wlds[WPM];               // 32 KB
    const int tid  = threadIdx.x;
    const int w    = tid >> 6;
    const int lane = tid & 63;
    const int r0 = blockIdx.x * 64 + w * 16;
    int rl = r0 + (lane & 15);
    if (rl >= n) rl = n - 1;
    const int kg = lane >> 4;

    {
        uint4* lds4 = (uint4*)wlds;
        const uint4* g = (const uint4*)Wp0;
        #pragma unroll
        for (int it = 0; it < 8; it++)
            lds4[it * 256 + tid] = g[it * 256 + tid];
    }

    f32x4 acc[8];
    #pragma unroll
    for (int cb = 0; cb < 8; cb++) acc[cb] = (f32x4)(0.f);

    v8bf af[4];
    #pragma unroll
    for (int kc = 0; kc < 4; kc++) {
        const float* ap = x + (size_t)rl * 128 + kc * 32 + kg * 8;
        float4 a0 = *(const float4*)ap;
        float4 a1 = *(const float4*)(ap + 4);
        v8bf v;
        v[0] = (__bf16)a0.x; v[1] = (__bf16)a0.y;
        v[2] = (__bf16)a0.z; v[3] = (__bf16)a0.w;
        v[4] = (__bf16)a1.x; v[5] = (__bf16)a1.y;
        v[6] = (__bf16)a1.z; v[7] = (__bf16)a1.w;
        af[kc] = v;
    }
    __syncthreads();

    #pragma unroll
    for (int kc = 0; kc < 4; kc++) {
        #pragma unroll
        for (int cb = 0; cb < 8; cb++) {
            int bo = ((kc * 8 + cb) * 64 + lane) * 8;
            acc[cb] = __builtin_amdgcn_mfma_f32_16x16x32_bf16(
                af[kc], *(const v8bf*)&wlds[bo], acc[cb], 0, 0, 0);
        }
    }
    int cl = lane & 15;
    #pragma unroll
    for (int cb = 0; cb < 8; cb++) {
        float bias = pre_b[cb * 16 + cl];
        #pragma unroll
        for (int j = 0; j < 4; j++) {
            int r = r0 + kg * 4 + j;
            if (r < n) hb[(size_t)r * 128 + cb * 16 + cl] = (__bf16)(acc[cb][j] + bias);
        }
    }
}

// ---------------------------------------------------------------------------
// LAYER GEMM: single K=384 MFMA stream (conv softmax folded into weights),
// B-fragments staged in LDS (two 48KB phases). Then LN blend + act blend.
// ---------------------------------------------------------------------------
__global__ __launch_bounds__(256, 3) void layer_gemm_kernel(
    const __bf16* __restrict__ aggGb, const __bf16* __restrict__ hin,
    const __bf16* __restrict__ meanb,
    const __bf16* __restrict__ WpG, const __bf16* __restrict__ WpS,
    const __bf16* __restrict__ WpN,
    const float* __restrict__ gcn_b,
    const float* __restrict__ lng, const float* __restrict__ lnb,
    const float* __restrict__ anorm, const float* __restrict__ aact,
    const float* __restrict__ aconv,
    __bf16* __restrict__ hout, int n)
{
    __shared__ __bf16 wlds[3 * 16 * 64 * 8];   // 48 KB
    const int tid  = threadIdx.x;
    const int w    = tid >> 6;
    const int lane = tid & 63;
    const int r0 = blockIdx.x * 64 + w * 16;
    int rl = r0 + (lane & 15);
    if (rl >= n) rl = n - 1;
    const int kg = lane >> 4;

    v8bf af[12];
    #pragma unroll
    for (int kc = 0; kc < 4; kc++) {
        size_t ao = (size_t)rl * 128 + kc * 32 + kg * 8;
        af[kc]     = *(const v8bf*)(aggGb + ao);
        af[4 + kc] = *(const v8bf*)(hin   + ao);
        af[8 + kc] = *(const v8bf*)(meanb + ao);
    }

    f32x4 acc[8];
    #pragma unroll
    for (int cb = 0; cb < 8; cb++) acc[cb] = (f32x4)(0.f);

    uint4* lds4 = (uint4*)wlds;

    {
        const uint4* gG = (const uint4*)WpG;
        const uint4* gS = (const uint4*)WpS;
        const uint4* gN = (const uint4*)WpN;
        #pragma unroll
        for (int it = 0; it < 12; it++) {
            int idx = it * 256 + tid;
            int m = idx >> 10;
            int r = idx & 1023;
            const uint4* g = (m == 0) ? gG : (m == 1) ? gS : gN;
            lds4[idx] = g[r];
        }
    }
    __syncthreads();
    #pragma unroll
    for (int kc2 = 0; kc2 < 2; kc2++) {
        #pragma unroll
        for (int cb = 0; cb < 8; cb++) {
            int bo = ((kc2 * 8 + cb) * 64 + lane) * 8;
            acc[cb] = __builtin_amdgcn_mfma_f32_16x16x32_bf16(
                af[kc2], *(const v8bf*)&wlds[bo], acc[cb], 0, 0, 0);
            acc[cb] = __builtin_amdgcn_mfma_f32_16x16x32_bf16(
                af[4 + kc2], *(const v8bf*)&wlds[8192 + bo], acc[cb], 0, 0, 0);
            acc[cb] = __builtin_amdgcn_mfma_f32_16x16x32_bf16(
                af[8 + kc2], *(const v8bf*)&wlds[16384 + bo], acc[cb], 0, 0, 0);
        }
    }
    __syncthreads();

    {
        const uint4* gG = (const uint4*)WpG + 1024;
        const uint4* gS = (const uint4*)WpS + 1024;
        const uint4* gN = (const uint4*)WpN + 1024;
        #pragma unroll
        for (int it = 0; it < 12; it++) {
            int idx = it * 256 + tid;
            int m = idx >> 10;
            int r = idx & 1023;
            const uint4* g = (m == 0) ? gG : (m == 1) ? gS : gN;
            lds4[idx] = g[r];
        }
    }
    __syncthreads();
    #pragma unroll
    for (int kc2 = 0; kc2 < 2; kc2++) {
        #pragma unroll
        for (int cb = 0; cb < 8; cb++) {
            int bo = ((kc2 * 8 + cb) * 64 + lane) * 8;
            acc[cb] = __builtin_amdgcn_mfma_f32_16x16x32_bf16(
                af[2 + kc2], *(const v8bf*)&wlds[bo], acc[cb], 0, 0, 0);
            acc[cb] = __builtin_amdgcn_mfma_f32_16x16x32_bf16(
                af[6 + kc2], *(const v8bf*)&wlds[8192 + bo], acc[cb], 0, 0, 0);
            acc[cb] = __builtin_amdgcn_mfma_f32_16x16x32_bf16(
                af[10 + kc2], *(const v8bf*)&wlds[16384 + bo], acc[cb], 0, 0, 0);
        }
    }

    float c0 = aconv[0], c1 = aconv[1];
    float m = fmaxf(c0, c1);
    float e0 = __expf(c0 - m), e1 = __expf(c1 - m);
    float wc0 = e0 / (e0 + e1);
    float q0 = anorm[0], q1 = anorm[1];
    m = fmaxf(q0, q1);
    e0 = __expf(q0 - m); e1 = __expf(q1 - m);
    float wn0 = e0 / (e0 + e1), wn1 = 1.f - wn0;
    float a0 = aact[0], a1 = aact[1], a2 = aact[2];
    m = fmaxf(fmaxf(a0, a1), a2);
    float f0 = __expf(a0 - m), f1 = __expf(a1 - m), f2 = __expf(a2 - m);
    float fs = 1.f / (f0 + f1 + f2);
    float wa0 = f0 * fs, wa1 = f1 * fs, wa2 = f2 * fs;

    int cl = lane & 15;
    float gbF[8], lg[8], lb[8];
    #pragma unroll
    for (int cb = 0; cb < 8; cb++) {
        int c = cb * 16 + cl;
        gbF[cb] = wc0 * gcn_b[c]; lg[cb] = lng[c]; lb[cb] = lnb[c];
    }

    float s[4] = {0, 0, 0, 0}, s2[4] = {0, 0, 0, 0};
    #pragma unroll
    for (int cb = 0; cb < 8; cb++)
        #pragma unroll
        for (int j = 0; j < 4; j++) {
            float tv = acc[cb][j] + gbF[cb];
            acc[cb][j] = tv;
            s[j] += tv;
            s2[j] = fmaf(tv, tv, s2[j]);
        }
    #pragma unroll
    for (int o = 1; o < 16; o <<= 1)
        #pragma unroll
        for (int j = 0; j < 4; j++) {
            s[j]  += __shfl_xor(s[j], o);
            s2[j] += __shfl_xor(s2[j], o);
        }
    float mu[4], rs[4];
    #pragma unroll
    for (int j = 0; j < 4; j++) {
        mu[j] = s[j] * (1.f / 128.f);
        float var = s2[j] * (1.f / 128.f) - mu[j] * mu[j];
        rs[j] = rsqrtf(var + EPSV);
    }

    #pragma unroll
    for (int j = 0; j < 4; j++) {
        int r = r0 + kg * 4 + j;
        if (r >= n) continue;
        #pragma unroll
        for (int cb = 0; cb < 8; cb++) {
            float tv = acc[cb][j];
            float ln = (tv - mu[j]) * rs[j] * lg[cb] + lb[cb];
            float hv = wn0 * ln + wn1 * tv;
            float rl_ = fmaxf(hv, 0.f);
            float ex2 = __expf(2.f * hv);
            float th = 1.f - 2.f * __builtin_amdgcn_rcpf(ex2 + 1.f);
            float el = hv > 0.f ? hv : __expf(hv) - 1.f;
            float out = wa0 * rl_ + wa1 * th + wa2 * el;
            hout[(size_t)r * 128 + cb * 16 + cl] = (__bf16)out;
        }
    }
}

// ---------------------------------------------------------------------------
// Pooling: sum h1+h2 (bf16), batch sorted -> run-length accumulate.
// ---------------------------------------------------------------------------
__global__ __launch_bounds__(256) void pool_sum_kernel(
    const __bf16* __restrict__ h1, const __bf16* __restrict__ h2,
    const int* __restrict__ batch, float* __restrict__ pooled, int n)
{
    int c2  = (threadIdx.x & 63) * 2;
    int seg = threadIdx.x >> 6;
    int n0  = blockIdx.x * 128 + seg * 32;
    int g_cur = -1;
    float acc0 = 0.f, acc1 = 0.f;
    for (int i = 0; i < 32; i++) {
        int node = n0 + i;
        if (node >= n) break;
        int g = batch[node];
        if (g != g_cur) {
            if (g_cur >= 0) {
                atomicAdd(&pooled[(size_t)g_cur * 128 + c2], acc0);
                atomicAdd(&pooled[(size_t)g_cur * 128 + c2 + 1], acc1);
            }
            g_cur = g; acc0 = 0.f; acc1 = 0.f;
        }
        unsigned u1 = *(const unsigned*)(h1 + (size_t)node * 128 + c2);
        unsigned u2 = *(const unsigned*)(h2 + (size_t)node * 128 + c2);
        acc0 += bf_lo(u1) + bf_lo(u2);
        acc1 += bf_hi(u1) + bf_hi(u2);
    }
    if (g_cur >= 0) {
        atomicAdd(&pooled[(size_t)g_cur * 128 + c2], acc0);
        atomicAdd(&pooled[(size_t)g_cur * 128 + c2 + 1], acc1);
    }
}

__global__ __launch_bounds__(64) void post_gemm_kernel(
    const float* __restrict__ pooled, const float* __restrict__ W,
    const float* __restrict__ b, float* __restrict__ out)
{
    __shared__ float p_s[128];
    int g = blockIdx.x;
    int j = threadIdx.x;
    p_s[j]      = pooled[(size_t)g * 128 + j];
    p_s[j + 64] = pooled[(size_t)g * 128 + 64 + j];
    __syncthreads();
    float acc = b[j];
    #pragma unroll
    for (int k = 0; k < 128; k++)
        acc = fmaf(p_s[k], W[k * 64 + j], acc);
    out[(size_t)g * 64 + j] = acc;
}

// ---------------------------------------------------------------------------
extern "C" void kernel_launch(void* const* d_in, const int* in_sizes, int n_in,
                              void* d_out, int out_size, void* d_ws, size_t ws_size,
                              hipStream_t stream)
{
    const float* x       = (const float*)d_in[0];
    const int*   ei      = (const int*)d_in[1];
    const int*   batch   = (const int*)d_in[2];
    const float* pre_w   = (const float*)d_in[3];
    const float* pre_b   = (const float*)d_in[4];
    const float* post_w  = (const float*)d_in[5];
    const float* post_b  = (const float*)d_in[6];
    const float* gcn_w   = (const float*)d_in[7];
    const float* gcn_b   = (const float*)d_in[8];
    const float* sage_ws = (const float*)d_in[9];
    const float* sage_wn = (const float*)d_in[10];
    const float* ln_g    = (const float*)d_in[11];
    const float* ln_b    = (const float*)d_in[12];
    const float* a_conv  = (const float*)d_in[13];
    const float* a_norm  = (const float*)d_in[14];
    const float* a_act   = (const float*)d_in[15];

    const int* src = ei;
    const int* dst = ei + N_EDGES;

    char* wsp = (char*)d_ws;
    size_t off = 0;
    auto alloc = [&](size_t bytes) {
        char* p = wsp + off;
        off += (bytes + 255) & ~(size_t)255;
        return p;
    };
    const size_t NHB = (size_t)N_NODES * 128 * sizeof(__bf16);   // 12.8 MB
    __bf16* hb0    = (__bf16*)alloc(NHB);
    __bf16* h1b    = (__bf16*)alloc(NHB);
    __bf16* h2b    = (__bf16*)alloc(NHB);
    __bf16* aggGb  = (__bf16*)alloc(NHB);
    __bf16* meanb  = (__bf16*)alloc(NHB);
    __bf16* Wp     = (__bf16*)alloc((size_t)7 * WPM * sizeof(__bf16));
    float*  dinv   = (float*)alloc(N_NODES * sizeof(float));
    int*    cnt    = (int*)alloc(N_NODES * sizeof(int));
    int*    ofs    = (int*)alloc((N_NODES + 1) * sizeof(int));
    int*    cursor = (int*)alloc(N_NODES * sizeof(int));
    int4*   hdr    = (int4*)alloc((size_t)N_NODES * sizeof(int4));
    int2*   csr    = (int2*)alloc((size_t)N_EDGES * sizeof(int2));
    float*  pooled = (float*)alloc((size_t)G_GRAPHS * 128 * sizeof(float));
    int*    btot   = (int*)alloc(64 * sizeof(int));
    int*    bbase  = (int*)alloc(64 * sizeof(int));

    const int NB_SCAN = (N_NODES + 1023) / 1024;
    const int GEMM_BLOCKS = (N_NODES + 63) / 64;
    const int GATHER_BLOCKS = (N_NODES + 3) / 4;

    setup_kernel<<<(G_GRAPHS * 128 + 255) / 256, 256, 0, stream>>>(
        pre_w, gcn_w, sage_ws, sage_wn, a_conv, Wp, cnt, pooled);

    count_deg_kernel<<<(N_EDGES + 255) / 256, 256, 0, stream>>>(dst, cnt, N_EDGES);
    scan_block_kernel<<<NB_SCAN, 1024, 0, stream>>>(cnt, ofs, btot, N_NODES);
    scan_tot_kernel<<<1, 64, 0, stream>>>(btot, bbase, NB_SCAN);
    scan_add_kernel<<<(N_NODES + 255) / 256, 256, 0, stream>>>(
        ofs, cursor, bbase, cnt, dinv, hdr, N_NODES);
    csr_fill_kernel<<<(N_EDGES + 255) / 256, 256, 0, stream>>>(
        src, dst, cursor, dinv, csr, N_EDGES);

    pre_gemm_mfma<<<GEMM_BLOCKS, 256, 0, stream>>>(x, Wp, pre_b, hb0, N_NODES);

    const __bf16* hin[2]  = { hb0, h1b };
    __bf16*       hout[2] = { h1b, h2b };
    for (int l = 0; l < 2; l++) {
        fused_gather_bf16<<<GATHER_BLOCKS, 256, 0, stream>>>(
            hin[l], csr, hdr, aggGb, meanb, N_NODES);
        layer_gemm_kernel<<<GEMM_BLOCKS, 256, 0, stream>>>(
            aggGb, hin[l], meanb,
            Wp + (size_t)(1 + l) * WPM, Wp + (size_t)(3 + l) * WPM, Wp + (size_t)(5 + l) * WPM,
            gcn_b + l * 128, ln_g + l * 128, ln_b + l * 128,
            a_norm + l * 2, a_act + l * 3, a_conv + l * 2,
            hout[l], N_NODES);
    }

    pool_sum_kernel<<<(N_NODES + 127) / 128, 256, 0, stream>>>(h1b, h2b, batch, pooled, N_NODES);
    post_gemm_kernel<<<G_GRAPHS, 64, 0, stream>>>(pooled, post_w, post_b, (float*)d_out);
}

// Round 9
// 207.064 us; speedup vs baseline: 1.0735x; 1.0568x over previous
//
#include <hip/hip_runtime.h>
#include <hip/hip_fp16.h>
#include <math.h>

#define N_NODES 50000
#define N_EDGES 640000
#define HDIM    128
#define D_OUT   64
#define G_GRAPHS 500
#define EPSV    1e-5f
#define WPM     16384   // elements per packed 128x128 weight matrix

typedef __bf16 v8bf __attribute__((ext_vector_type(8)));
typedef float  f32x4 __attribute__((ext_vector_type(4)));

static __device__ __forceinline__ float bf_lo(unsigned u) {
    union { unsigned x; float f; } c; c.x = u << 16; return c.f;
}
static __device__ __forceinline__ float bf_hi(unsigned u) {
    union { unsigned x; float f; } c; c.x = u & 0xffff0000u; return c.f;
}

// ---------------------------------------------------------------------------
// Setup: zero cnt+pooled AND pack 7 f32 128x128 weights into bf16 MFMA
// B-fragment order with conv-softmax folded in:
//   m=0: pre_w   m=1,2: wc0[l]*gcn_w[l]  m=3,4: wc1[l]*sage_ws[l]
//   m=5,6: wc1[l]*sage_wn[l]
// ---------------------------------------------------------------------------
__global__ void setup_kernel(const float* __restrict__ pre_w,
                             const float* __restrict__ gcn_w,
                             const float* __restrict__ sws,
                             const float* __restrict__ swn,
                             const float* __restrict__ a_conv,
                             __bf16* __restrict__ Wp,
                             int* __restrict__ cnt,
                             float* __restrict__ pooled)
{
    int t = blockIdx.x * blockDim.x + threadIdx.x;
    if (t < N_NODES) cnt[t] = 0;
    if (t < G_GRAPHS * 128) pooled[t] = 0.f;
    if (t >= 7 * 2048) return;
    int m    = t >> 11;
    int r    = t & 2047;
    int lane = r & 63;
    int fb   = r >> 6;           // kc*8 + cb
    int kc   = fb >> 3;
    int cb   = fb & 7;
    const float* W = pre_w;
    float scale = 1.f;
    if (m > 0) {
        int type = (m - 1) >> 1;     // 0=gcn, 1=sage_ws, 2=sage_wn
        int l    = (m - 1) & 1;
        float c0 = a_conv[l * 2], c1 = a_conv[l * 2 + 1];
        float mx = fmaxf(c0, c1);
        float e0 = __expf(c0 - mx), e1 = __expf(c1 - mx);
        float wc0 = e0 / (e0 + e1);
        scale = (type == 0) ? wc0 : (1.f - wc0);
        W = (type == 0) ? gcn_w + (size_t)l * WPM
          : (type == 1) ? sws   + (size_t)l * WPM
                        : swn   + (size_t)l * WPM;
    }
    int k0  = kc * 32 + (lane >> 4) * 8;
    int col = cb * 16 + (lane & 15);
    __bf16* out = Wp + (size_t)m * WPM + ((size_t)fb * 64 + lane) * 8;
    #pragma unroll
    for (int i = 0; i < 8; i++)
        out[i] = (__bf16)(scale * W[(size_t)(k0 + i) * 128 + col]);
}

// ---------------------------------------------------------------------------
// Degrees
// ---------------------------------------------------------------------------
__global__ void count_deg_kernel(const int* __restrict__ dst, int* __restrict__ cnt, int E) {
    int i = blockIdx.x * blockDim.x + threadIdx.x;
    if (i < E) atomicAdd(&cnt[dst[i]], 1);
}

// ---------------------------------------------------------------------------
// 3-phase parallel exclusive scan; final phase emits packed per-node header
// hdr[i] = {beg, end, dinv_bits, rdegn_bits} and cursor/dinv for csr_fill.
// ---------------------------------------------------------------------------
__global__ __launch_bounds__(1024) void scan_block_kernel(
    const int* __restrict__ cnt, int* __restrict__ ofs,
    int* __restrict__ btot, int n)
{
    __shared__ int wsum[16];
    const int tid  = threadIdx.x;
    const int lane = tid & 63;
    const int wid  = tid >> 6;
    int i = blockIdx.x * 1024 + tid;
    int v = (i < n) ? cnt[i] : 0;
    int x = v;
    #pragma unroll
    for (int o = 1; o < 64; o <<= 1) {
        int t = __shfl_up(x, o);
        if (lane >= o) x += t;
    }
    if (lane == 63) wsum[wid] = x;
    __syncthreads();
    if (wid == 0) {
        int y = (lane < 16) ? wsum[lane] : 0;
        #pragma unroll
        for (int o = 1; o < 16; o <<= 1) {
            int t = __shfl_up(y, o);
            if (lane >= o) y += t;
        }
        if (lane < 16) wsum[lane] = y;
    }
    __syncthreads();
    int wbase = (wid == 0) ? 0 : wsum[wid - 1];
    if (i < n) ofs[i] = wbase + x - v;      // chunk-local exclusive
    if (tid == 1023) btot[blockIdx.x] = wbase + x;
}

__global__ __launch_bounds__(64) void scan_tot_kernel(
    const int* __restrict__ btot, int* __restrict__ bbase, int nb)
{
    int i = threadIdx.x;
    int v = (i < nb) ? btot[i] : 0;
    int x = v;
    #pragma unroll
    for (int o = 1; o < 64; o <<= 1) {
        int t = __shfl_up(x, o);
        if (i >= o) x += t;
    }
    if (i < nb) bbase[i] = x - v;
}

__global__ void scan_add_kernel(const int* __restrict__ ofs,
                                int* __restrict__ cursor,
                                const int* __restrict__ bbase,
                                const int* __restrict__ cnt,
                                float* __restrict__ dinv,
                                int4* __restrict__ hdr, int n) {
    int i = blockIdx.x * blockDim.x + threadIdx.x;
    if (i < n) {
        int o = ofs[i] + bbase[i >> 10];
        cursor[i] = o;
        int c = cnt[i];
        float cf = (float)c;
        float di = rsqrtf(cf + 1.0f);
        float rd = 1.0f / fmaxf(cf, 1.0f);
        dinv[i] = di;
        hdr[i] = make_int4(o, o + c, __float_as_int(di), __float_as_int(rd));
    }
}

// ---------------------------------------------------------------------------
// CSR fill with 4-byte packed entries: (src << 16) | fp16(dinv[src]).
// src < 50000 fits in 16 bits; 4B scattered stores halve the HBM write
// amplification vs 8B int2 (partial-line writeback from 8 XCD L2s).
// ---------------------------------------------------------------------------
__global__ void csr_fill_kernel(const int* __restrict__ src, const int* __restrict__ dst,
                                int* __restrict__ cursor, const float* __restrict__ dinv,
                                unsigned* __restrict__ csr, int E) {
    int e = blockIdx.x * blockDim.x + threadIdx.x;
    if (e < E) {
        int s = src[e];
        int d = dst[e];
        int pos = atomicAdd(&cursor[d], 1);
        unsigned short hw = __half_as_ushort(__float2half(dinv[s]));
        csr[pos] = ((unsigned)s << 16) | (unsigned)hw;
    }
}

// ---------------------------------------------------------------------------
// Pull-gather (bf16): one wave per dst node, packed header (one int4 load),
// 16 edges per iteration, 4B packed csr entries (src|fp16 dinv).
// ---------------------------------------------------------------------------
__global__ __launch_bounds__(256) void fused_gather_bf16(
    const __bf16* __restrict__ hb,
    const unsigned* __restrict__ csr,
    const int4* __restrict__ hdr,
    __bf16* __restrict__ aggGb,
    __bf16* __restrict__ meanb, int n)
{
    int w = threadIdx.x >> 6;
    int lane = threadIdx.x & 63;
    int d = blockIdx.x * 4 + w;
    if (d >= n) return;
    int4 h4 = hdr[d];
    int beg = h4.x, end = h4.y;
    float did = __int_as_float(h4.z);
    float rd  = __int_as_float(h4.w);
    int q  = lane >> 4;
    int c8 = (lane & 15) * 8;

    float aG[8] = {0, 0, 0, 0, 0, 0, 0, 0};
    float aS[8] = {0, 0, 0, 0, 0, 0, 0, 0};

    for (int p = beg; p < end; p += 16) {
        bool ok[4];
        unsigned e[4];
        #pragma unroll
        for (int k = 0; k < 4; k++) {
            int idx = p + 4 * k + q;
            ok[k] = idx < end;
            e[k] = csr[ok[k] ? idx : beg];
        }
        uint4 u[4];
        #pragma unroll
        for (int k = 0; k < 4; k++)
            u[k] = *(const uint4*)(hb + (size_t)(e[k] >> 16) * 128 + c8);
        #pragma unroll
        for (int k = 0; k < 4; k++) {
            float ds = __half2float(__ushort_as_half((unsigned short)(e[k] & 0xffffu)));
            float wk = ok[k] ? ds * did : 0.f;
            float mk = ok[k] ? 1.f : 0.f;
            float v[8] = { bf_lo(u[k].x), bf_hi(u[k].x), bf_lo(u[k].y), bf_hi(u[k].y),
                           bf_lo(u[k].z), bf_hi(u[k].z), bf_lo(u[k].w), bf_hi(u[k].w) };
            #pragma unroll
            for (int j = 0; j < 8; j++) {
                aG[j] = fmaf(v[j], wk, aG[j]);
                aS[j] = fmaf(v[j], mk, aS[j]);
            }
        }
    }
    #pragma unroll
    for (int j = 0; j < 8; j++) {
        aG[j] += __shfl_xor(aG[j], 16);
        aG[j] += __shfl_xor(aG[j], 32);
        aS[j] += __shfl_xor(aS[j], 16);
        aS[j] += __shfl_xor(aS[j], 32);
    }
    if (q == 0) {
        uint4 ud = *(const uint4*)(hb + (size_t)d * 128 + c8);
        float vd[8] = { bf_lo(ud.x), bf_hi(ud.x), bf_lo(ud.y), bf_hi(ud.y),
                        bf_lo(ud.z), bf_hi(ud.z), bf_lo(ud.w), bf_hi(ud.w) };
        float sl = did * did;
        union { __bf16 b[8]; uint4 u; } pg, pm;
        #pragma unroll
        for (int j = 0; j < 8; j++) {
            pg.b[j] = (__bf16)fmaf(vd[j], sl, aG[j]);
            pm.b[j] = (__bf16)(aS[j] * rd);
        }
        *(uint4*)(aggGb + (size_t)d * 128 + c8) = pg.u;
        *(uint4*)(meanb + (size_t)d * 128 + c8) = pm.u;
    }
}

// ---------------------------------------------------------------------------
// Pre-MLP: h_bf16 = x_f32 @ pre_w + pre_b, via MFMA; pre_w staged in LDS.
// ---------------------------------------------------------------------------
__global__ __launch_bounds__(256) void pre_gemm_mfma(
    const float* __restrict__ x, const __bf16* __restrict__ Wp0,
    const float* __restrict__ pre_b, __bf16* __restrict__ hb, int n)
{
    __shared__ __bf16 wlds[WPM];               // 32 KB
    const int tid  = threadIdx.x;
    const int w    = tid >> 6;
    const int lane = tid & 63;
    const int r0 = blockIdx.x * 64 + w * 16;
    int rl = r0 + (lane & 15);
    if (rl >= n) rl = n - 1;
    const int kg = lane >> 4;

    {
        uint4* lds4 = (uint4*)wlds;
        const uint4* g = (const uint4*)Wp0;
        #pragma unroll
        for (int it = 0; it < 8; it++)
            lds4[it * 256 + tid] = g[it * 256 + tid];
    }

    f32x4 acc[8];
    #pragma unroll
    for (int cb = 0; cb < 8; cb++) acc[cb] = (f32x4)(0.f);

    v8bf af[4];
    #pragma unroll
    for (int kc = 0; kc < 4; kc++) {
        const float* ap = x + (size_t)rl * 128 + kc * 32 + kg * 8;
        float4 a0 = *(const float4*)ap;
        float4 a1 = *(const float4*)(ap + 4);
        v8bf v;
        v[0] = (__bf16)a0.x; v[1] = (__bf16)a0.y;
        v[2] = (__bf16)a0.z; v[3] = (__bf16)a0.w;
        v[4] = (__bf16)a1.x; v[5] = (__bf16)a1.y;
        v[6] = (__bf16)a1.z; v[7] = (__bf16)a1.w;
        af[kc] = v;
    }
    __syncthreads();

    #pragma unroll
    for (int kc = 0; kc < 4; kc++) {
        #pragma unroll
        for (int cb = 0; cb < 8; cb++) {
            int bo = ((kc * 8 + cb) * 64 + lane) * 8;
            acc[cb] = __builtin_amdgcn_mfma_f32_16x16x32_bf16(
                af[kc], *(const v8bf*)&wlds[bo], acc[cb], 0, 0, 0);
        }
    }
    int cl = lane & 15;
    #pragma unroll
    for (int cb = 0; cb < 8; cb++) {
        float bias = pre_b[cb * 16 + cl];
        #pragma unroll
        for (int j = 0; j < 4; j++) {
            int r = r0 + kg * 4 + j;
            if (r < n) hb[(size_t)r * 128 + cb * 16 + cl] = (__bf16)(acc[cb][j] + bias);
        }
    }
}

// ---------------------------------------------------------------------------
// LAYER GEMM: single K=384 MFMA stream (conv softmax folded into weights),
// B-fragments staged in LDS (two 48KB phases). Then LN blend + act blend.
// ---------------------------------------------------------------------------
__global__ __launch_bounds__(256, 3) void layer_gemm_kernel(
    const __bf16* __restrict__ aggGb, const __bf16* __restrict__ hin,
    const __bf16* __restrict__ meanb,
    const __bf16* __restrict__ WpG, const __bf16* __restrict__ WpS,
    const __bf16* __restrict__ WpN,
    const float* __restrict__ gcn_b,
    const float* __restrict__ lng, const float* __restrict__ lnb,
    const float* __restrict__ anorm, const float* __restrict__ aact,
    const float* __restrict__ aconv,
    __bf16* __restrict__ hout, int n)
{
    __shared__ __bf16 wlds[3 * 16 * 64 * 8];   // 48 KB
    const int tid  = threadIdx.x;
    const int w    = tid >> 6;
    const int lane = tid & 63;
    const int r0 = blockIdx.x * 64 + w * 16;
    int rl = r0 + (lane & 15);
    if (rl >= n) rl = n - 1;
    const int kg = lane >> 4;

    v8bf af[12];
    #pragma unroll
    for (int kc = 0; kc < 4; kc++) {
        size_t ao = (size_t)rl * 128 + kc * 32 + kg * 8;
        af[kc]     = *(const v8bf*)(aggGb + ao);
        af[4 + kc] = *(const v8bf*)(hin   + ao);
        af[8 + kc] = *(const v8bf*)(meanb + ao);
    }

    f32x4 acc[8];
    #pragma unroll
    for (int cb = 0; cb < 8; cb++) acc[cb] = (f32x4)(0.f);

    uint4* lds4 = (uint4*)wlds;

    {
        const uint4* gG = (const uint4*)WpG;
        const uint4* gS = (const uint4*)WpS;
        const uint4* gN = (const uint4*)WpN;
        #pragma unroll
        for (int it = 0; it < 12; it++) {
            int idx = it * 256 + tid;
            int m = idx >> 10;
            int r = idx & 1023;
            const uint4* g = (m == 0) ? gG : (m == 1) ? gS : gN;
            lds4[idx] = g[r];
        }
    }
    __syncthreads();
    #pragma unroll
    for (int kc2 = 0; kc2 < 2; kc2++) {
        #pragma unroll
        for (int cb = 0; cb < 8; cb++) {
            int bo = ((kc2 * 8 + cb) * 64 + lane) * 8;
            acc[cb] = __builtin_amdgcn_mfma_f32_16x16x32_bf16(
                af[kc2], *(const v8bf*)&wlds[bo], acc[cb], 0, 0, 0);
            acc[cb] = __builtin_amdgcn_mfma_f32_16x16x32_bf16(
                af[4 + kc2], *(const v8bf*)&wlds[8192 + bo], acc[cb], 0, 0, 0);
            acc[cb] = __builtin_amdgcn_mfma_f32_16x16x32_bf16(
                af[8 + kc2], *(const v8bf*)&wlds[16384 + bo], acc[cb], 0, 0, 0);
        }
    }
    __syncthreads();

    {
        const uint4* gG = (const uint4*)WpG + 1024;
        const uint4* gS = (const uint4*)WpS + 1024;
        const uint4* gN = (const uint4*)WpN + 1024;
        #pragma unroll
        for (int it = 0; it < 12; it++) {
            int idx = it * 256 + tid;
            int m = idx >> 10;
            int r = idx & 1023;
            const uint4* g = (m == 0) ? gG : (m == 1) ? gS : gN;
            lds4[idx] = g[r];
        }
    }
    __syncthreads();
    #pragma unroll
    for (int kc2 = 0; kc2 < 2; kc2++) {
        #pragma unroll
        for (int cb = 0; cb < 8; cb++) {
            int bo = ((kc2 * 8 + cb) * 64 + lane) * 8;
            acc[cb] = __builtin_amdgcn_mfma_f32_16x16x32_bf16(
                af[2 + kc2], *(const v8bf*)&wlds[bo], acc[cb], 0, 0, 0);
            acc[cb] = __builtin_amdgcn_mfma_f32_16x16x32_bf16(
                af[6 + kc2], *(const v8bf*)&wlds[8192 + bo], acc[cb], 0, 0, 0);
            acc[cb] = __builtin_amdgcn_mfma_f32_16x16x32_bf16(
                af[10 + kc2], *(const v8bf*)&wlds[16384 + bo], acc[cb], 0, 0, 0);
        }
    }

    float c0 = aconv[0], c1 = aconv[1];
    float m = fmaxf(c0, c1);
    float e0 = __expf(c0 - m), e1 = __expf(c1 - m);
    float wc0 = e0 / (e0 + e1);
    float q0 = anorm[0], q1 = anorm[1];
    m = fmaxf(q0, q1);
    e0 = __expf(q0 - m); e1 = __expf(q1 - m);
    float wn0 = e0 / (e0 + e1), wn1 = 1.f - wn0;
    float a0 = aact[0], a1 = aact[1], a2 = aact[2];
    m = fmaxf(fmaxf(a0, a1), a2);
    float f0 = __expf(a0 - m), f1 = __expf(a1 - m), f2 = __expf(a2 - m);
    float fs = 1.f / (f0 + f1 + f2);
    float wa0 = f0 * fs, wa1 = f1 * fs, wa2 = f2 * fs;

    int cl = lane & 15;
    float gbF[8], lg[8], lb[8];
    #pragma unroll
    for (int cb = 0; cb < 8; cb++) {
        int c = cb * 16 + cl;
        gbF[cb] = wc0 * gcn_b[c]; lg[cb] = lng[c]; lb[cb] = lnb[c];
    }

    float s[4] = {0, 0, 0, 0}, s2[4] = {0, 0, 0, 0};
    #pragma unroll
    for (int cb = 0; cb < 8; cb++)
        #pragma unroll
        for (int j = 0; j < 4; j++) {
            float tv = acc[cb][j] + gbF[cb];
            acc[cb][j] = tv;
            s[j] += tv;
            s2[j] = fmaf(tv, tv, s2[j]);
        }
    #pragma unroll
    for (int o = 1; o < 16; o <<= 1)
        #pragma unroll
        for (int j = 0; j < 4; j++) {
            s[j]  += __shfl_xor(s[j], o);
            s2[j] += __shfl_xor(s2[j], o);
        }
    float mu[4], rs[4];
    #pragma unroll
    for (int j = 0; j < 4; j++) {
        mu[j] = s[j] * (1.f / 128.f);
        float var = s2[j] * (1.f / 128.f) - mu[j] * mu[j];
        rs[j] = rsqrtf(var + EPSV);
    }

    #pragma unroll
    for (int j = 0; j < 4; j++) {
        int r = r0 + kg * 4 + j;
        if (r >= n) continue;
        #pragma unroll
        for (int cb = 0; cb < 8; cb++) {
            float tv = acc[cb][j];
            float ln = (tv - mu[j]) * rs[j] * lg[cb] + lb[cb];
            float hv = wn0 * ln + wn1 * tv;
            float rl_ = fmaxf(hv, 0.f);
            float ex2 = __expf(2.f * hv);
            float th = 1.f - 2.f * __builtin_amdgcn_rcpf(ex2 + 1.f);
            float el = hv > 0.f ? hv : __expf(hv) - 1.f;
            float out = wa0 * rl_ + wa1 * th + wa2 * el;
            hout[(size_t)r * 128 + cb * 16 + cl] = (__bf16)out;
        }
    }
}

// ---------------------------------------------------------------------------
// Pooling: sum h1+h2 (bf16), batch sorted -> run-length accumulate.
// ---------------------------------------------------------------------------
__global__ __launch_bounds__(256) void pool_sum_kernel(
    const __bf16* __restrict__ h1, const __bf16* __restrict__ h2,
    const int* __restrict__ batch, float* __restrict__ pooled, int n)
{
    int c2  = (threadIdx.x & 63) * 2;
    int seg = threadIdx.x >> 6;
    int n0  = blockIdx.x * 128 + seg * 32;
    int g_cur = -1;
    float acc0 = 0.f, acc1 = 0.f;
    for (int i = 0; i < 32; i++) {
        int node = n0 + i;
        if (node >= n) break;
        int g = batch[node];
        if (g != g_cur) {
            if (g_cur >= 0) {
                atomicAdd(&pooled[(size_t)g_cur * 128 + c2], acc0);
                atomicAdd(&pooled[(size_t)g_cur * 128 + c2 + 1], acc1);
            }
            g_cur = g; acc0 = 0.f; acc1 = 0.f;
        }
        unsigned u1 = *(const unsigned*)(h1 + (size_t)node * 128 + c2);
        unsigned u2 = *(const unsigned*)(h2 + (size_t)node * 128 + c2);
        acc0 += bf_lo(u1) + bf_lo(u2);
        acc1 += bf_hi(u1) + bf_hi(u2);
    }
    if (g_cur >= 0) {
        atomicAdd(&pooled[(size_t)g_cur * 128 + c2], acc0);
        atomicAdd(&pooled[(size_t)g_cur * 128 + c2 + 1], acc1);
    }
}

__global__ __launch_bounds__(64) void post_gemm_kernel(
    const float* __restrict__ pooled, const float* __restrict__ W,
    const float* __restrict__ b, float* __restrict__ out)
{
    __shared__ float p_s[128];
    int g = blockIdx.x;
    int j = threadIdx.x;
    p_s[j]      = pooled[(size_t)g * 128 + j];
    p_s[j + 64] = pooled[(size_t)g * 128 + 64 + j];
    __syncthreads();
    float acc = b[j];
    #pragma unroll
    for (int k = 0; k < 128; k++)
        acc = fmaf(p_s[k], W[k * 64 + j], acc);
    out[(size_t)g * 64 + j] = acc;
}

// ---------------------------------------------------------------------------
extern "C" void kernel_launch(void* const* d_in, const int* in_sizes, int n_in,
                              void* d_out, int out_size, void* d_ws, size_t ws_size,
                              hipStream_t stream)
{
    const float* x       = (const float*)d_in[0];
    const int*   ei      = (const int*)d_in[1];
    const int*   batch   = (const int*)d_in[2];
    const float* pre_w   = (const float*)d_in[3];
    const float* pre_b   = (const float*)d_in[4];
    const float* post_w  = (const float*)d_in[5];
    const float* post_b  = (const float*)d_in[6];
    const float* gcn_w   = (const float*)d_in[7];
    const float* gcn_b   = (const float*)d_in[8];
    const float* sage_ws = (const float*)d_in[9];
    const float* sage_wn = (const float*)d_in[10];
    const float* ln_g    = (const float*)d_in[11];
    const float* ln_b    = (const float*)d_in[12];
    const float* a_conv  = (const float*)d_in[13];
    const float* a_norm  = (const float*)d_in[14];
    const float* a_act   = (const float*)d_in[15];

    const int* src = ei;
    const int* dst = ei + N_EDGES;

    char* wsp = (char*)d_ws;
    size_t off = 0;
    auto alloc = [&](size_t bytes) {
        char* p = wsp + off;
        off += (bytes + 255) & ~(size_t)255;
        return p;
    };
    const size_t NHB = (size_t)N_NODES * 128 * sizeof(__bf16);   // 12.8 MB
    __bf16*   hb0    = (__bf16*)alloc(NHB);
    __bf16*   h1b    = (__bf16*)alloc(NHB);
    __bf16*   h2b    = (__bf16*)alloc(NHB);
    __bf16*   aggGb  = (__bf16*)alloc(NHB);
    __bf16*   meanb  = (__bf16*)alloc(NHB);
    __bf16*   Wp     = (__bf16*)alloc((size_t)7 * WPM * sizeof(__bf16));
    float*    dinv   = (float*)alloc(N_NODES * sizeof(float));
    int*      cnt    = (int*)alloc(N_NODES * sizeof(int));
    int*      ofs    = (int*)alloc((N_NODES + 1) * sizeof(int));
    int*      cursor = (int*)alloc(N_NODES * sizeof(int));
    int4*     hdr    = (int4*)alloc((size_t)N_NODES * sizeof(int4));
    unsigned* csr    = (unsigned*)alloc((size_t)N_EDGES * sizeof(unsigned));
    float*    pooled = (float*)alloc((size_t)G_GRAPHS * 128 * sizeof(float));
    int*      btot   = (int*)alloc(64 * sizeof(int));
    int*      bbase  = (int*)alloc(64 * sizeof(int));

    const int NB_SCAN = (N_NODES + 1023) / 1024;
    const int GEMM_BLOCKS = (N_NODES + 63) / 64;
    const int GATHER_BLOCKS = (N_NODES + 3) / 4;

    setup_kernel<<<(G_GRAPHS * 128 + 255) / 256, 256, 0, stream>>>(
        pre_w, gcn_w, sage_ws, sage_wn, a_conv, Wp, cnt, pooled);

    count_deg_kernel<<<(N_EDGES + 255) / 256, 256, 0, stream>>>(dst, cnt, N_EDGES);
    scan_block_kernel<<<NB_SCAN, 1024, 0, stream>>>(cnt, ofs, btot, N_NODES);
    scan_tot_kernel<<<1, 64, 0, stream>>>(btot, bbase, NB_SCAN);
    scan_add_kernel<<<(N_NODES + 255) / 256, 256, 0, stream>>>(
        ofs, cursor, bbase, cnt, dinv, hdr, N_NODES);
    csr_fill_kernel<<<(N_EDGES + 255) / 256, 256, 0, stream>>>(
        src, dst, cursor, dinv, csr, N_EDGES);

    pre_gemm_mfma<<<GEMM_BLOCKS, 256, 0, stream>>>(x, Wp, pre_b, hb0, N_NODES);

    const __bf16* hin[2]  = { hb0, h1b };
    __bf16*       hout[2] = { h1b, h2b };
    for (int l = 0; l < 2; l++) {
        fused_gather_bf16<<<GATHER_BLOCKS, 256, 0, stream>>>(
            hin[l], csr, hdr, aggGb, meanb, N_NODES);
        layer_gemm_kernel<<<GEMM_BLOCKS, 256, 0, stream>>>(
            aggGb, hin[l], meanb,
            Wp + (size_t)(1 + l) * WPM, Wp + (size_t)(3 + l) * WPM, Wp + (size_t)(5 + l) * WPM,
            gcn_b + l * 128, ln_g + l * 128, ln_b + l * 128,
            a_norm + l * 2, a_act + l * 3, a_conv + l * 2,
            hout[l], N_NODES);
    }

    pool_sum_kernel<<<(N_NODES + 127) / 128, 256, 0, stream>>>(h1b, h2b, batch, pooled, N_NODES);
    post_gemm_kernel<<<G_GRAPHS, 64, 0, stream>>>(pooled, post_w, post_b, (float*)d_out);
}